// Round 6
// baseline (596.273 us; speedup 1.0000x reference)
//
#include <hip/hip_runtime.h>

#define N_NODESC 50000
#define N_EDGESC 400000
#define N_GRAPHSC 128
#define IN_DIMC 768
#define HIDC 128
#define NCLSC 11
#define BN_EPSC 1e-5f
#define NB_AGG 8
#define NREP 64   // stats atomic replicas: 6250 blocks / 64 -> ~98-deep chains per address
#define SCAN_NB ((N_NODESC + 255) / 256)   // 196 blocks for the hierarchical scan

typedef __bf16 bf16_t;
typedef __bf16 bf16x8 __attribute__((ext_vector_type(8)));
typedef float f32x4 __attribute__((ext_vector_type(4)));

__device__ inline f32x4 mfma_16x16x32_bf16(bf16x8 a, bf16x8 b, f32x4 c) {
    return __builtin_amdgcn_mfma_f32_16x16x32_bf16(a, b, c, 0, 0, 0);
}

// [Cl | Cr] = BN?(A)[M,K] @ [Bl;Br]^T.  A fp32 row-major; Bl/Br [128,K] fp32.
// blockIdx.y==0 -> Cl bf16 [M,128]; blockIdx.y==1 -> Cr fp32 [M,128].
// M-tile 64, N-tile 128, BK 32. 4 waves in 2x2; wave tile 32x64 (2x4 MFMA tiles).
// Staging: thread t handles row t>>2, cols (t&3)*8 -> one ds_write_b128 each
// (bank-optimal; same distribution as the b128 read path).
template<bool APPLY_BN>
__global__ __launch_bounds__(256) void gemm_kernel(const float* __restrict__ A,
                                                   const float* __restrict__ Bl,
                                                   const float* __restrict__ Br,
                                                   const float* __restrict__ sc,
                                                   bf16_t* __restrict__ Cl,
                                                   float* __restrict__ Cr, int M, int K)
{
    __shared__ bf16_t As[64][40];    // pad 32->40: 16B-aligned b128, even-bank 2-way only
    __shared__ bf16_t Bs[128][40];

    const int t  = threadIdx.x;
    const int m0 = blockIdx.x * 64;
    const float* Bsel = (blockIdx.y == 0) ? Bl : Br;

    const int sr  = t >> 2;        // staging row 0..63
    const int sc8 = (t & 3) * 8;   // staging col 0,8,16,24

    const int wid  = t >> 6;
    const int lane = t & 63;
    const int wm   = (wid >> 1) * 32;
    const int wn   = (wid & 1) * 64;
    const int l16  = lane & 15;
    const int quad = lane >> 4;

    f32x4 acc[2][4] = {};

    for (int k0 = 0; k0 < K; k0 += 32) {
        // ---- A: 64x32 tile, one b128 write per thread ----
        {
            int am = m0 + sr; if (am > M - 1) am = M - 1;   // clamp (garbage rows never stored)
            const float* ap = &A[(size_t)am * K + k0 + sc8];
            float4 v0 = *(const float4*)ap;
            float4 v1 = *(const float4*)(ap + 4);
            if (APPLY_BN) {
                float4 s0 = *(const float4*)&sc[k0 + sc8];
                float4 s1 = *(const float4*)&sc[k0 + sc8 + 4];
                float4 h0 = *(const float4*)&sc[HIDC + k0 + sc8];
                float4 h1 = *(const float4*)&sc[HIDC + k0 + sc8 + 4];
                v0.x = fmaxf(fmaf(v0.x, s0.x, h0.x), 0.0f);
                v0.y = fmaxf(fmaf(v0.y, s0.y, h0.y), 0.0f);
                v0.z = fmaxf(fmaf(v0.z, s0.z, h0.z), 0.0f);
                v0.w = fmaxf(fmaf(v0.w, s0.w, h0.w), 0.0f);
                v1.x = fmaxf(fmaf(v1.x, s1.x, h1.x), 0.0f);
                v1.y = fmaxf(fmaf(v1.y, s1.y, h1.y), 0.0f);
                v1.z = fmaxf(fmaf(v1.z, s1.z, h1.z), 0.0f);
                v1.w = fmaxf(fmaf(v1.w, s1.w, h1.w), 0.0f);
            }
            bf16x8 bv;
            bv[0] = (bf16_t)v0.x; bv[1] = (bf16_t)v0.y; bv[2] = (bf16_t)v0.z; bv[3] = (bf16_t)v0.w;
            bv[4] = (bf16_t)v1.x; bv[5] = (bf16_t)v1.y; bv[6] = (bf16_t)v1.z; bv[7] = (bf16_t)v1.w;
            *(bf16x8*)&As[sr][sc8] = bv;
        }
        // ---- B: 128x32 tile, two b128 writes per thread ----
#pragma unroll
        for (int p = 0; p < 2; p++) {
            int br = sr + p * 64;
            const float* bp = &Bsel[(size_t)br * K + k0 + sc8];
            float4 v0 = *(const float4*)bp;
            float4 v1 = *(const float4*)(bp + 4);
            bf16x8 bv;
            bv[0] = (bf16_t)v0.x; bv[1] = (bf16_t)v0.y; bv[2] = (bf16_t)v0.z; bv[3] = (bf16_t)v0.w;
            bv[4] = (bf16_t)v1.x; bv[5] = (bf16_t)v1.y; bv[6] = (bf16_t)v1.z; bv[7] = (bf16_t)v1.w;
            *(bf16x8*)&Bs[br][sc8] = bv;
        }
        __syncthreads();

        bf16x8 af[2], bfr[4];
#pragma unroll
        for (int i = 0; i < 2; i++)
            af[i] = *(const bf16x8*)&As[wm + i * 16 + l16][quad * 8];
#pragma unroll
        for (int j = 0; j < 4; j++)
            bfr[j] = *(const bf16x8*)&Bs[wn + j * 16 + l16][quad * 8];
#pragma unroll
        for (int i = 0; i < 2; i++)
#pragma unroll
            for (int j = 0; j < 4; j++)
                acc[i][j] = mfma_16x16x32_bf16(af[i], bfr[j], acc[i][j]);
        __syncthreads();
    }

    // C/D layout (m89-verified): col = lane&15, row = quad*4 + reg
#pragma unroll
    for (int i = 0; i < 2; i++) {
        int rowb = m0 + wm + i * 16 + quad * 4;
#pragma unroll
        for (int j = 0; j < 4; j++) {
            int colh = wn + j * 16 + l16;   // 0..127 within the half
#pragma unroll
            for (int rr = 0; rr < 4; rr++) {
                int row = rowb + rr;
                if (row < M) {
                    if (blockIdx.y == 0) Cl[(size_t)row * HIDC + colh] = (bf16_t)acc[i][j][rr];
                    else                 Cr[(size_t)row * HIDC + colh] = acc[i][j][rr];
                }
            }
        }
    }
}

// ---------- CSR build ----------
__global__ void degi_kernel(const int* __restrict__ ei, int* __restrict__ degi) {
    int e = blockIdx.x * blockDim.x + threadIdx.x;
    if (e < N_EDGESC) atomicAdd(&degi[ei[N_EDGESC + e]], 1);
}

// hierarchical scan, phase 1: per-block exclusive scan of 256 elems + block total
__global__ __launch_bounds__(256) void scan1_kernel(const int* __restrict__ degi,
                                                    int* __restrict__ local,
                                                    int* __restrict__ partials)
{
    __shared__ int tmp[256];
    const int t = threadIdx.x;
    const int i = blockIdx.x * 256 + t;
    int v = (i < N_NODESC) ? degi[i] : 0;
    tmp[t] = v;
    __syncthreads();
    for (int off = 1; off < 256; off <<= 1) {
        int u = (t >= off) ? tmp[t - off] : 0;
        __syncthreads();
        tmp[t] += u;
        __syncthreads();
    }
    if (i < N_NODESC) local[i] = tmp[t] - v;          // exclusive-in-block
    if (t == 255) partials[blockIdx.x] = tmp[255];    // block total
}

// phase 2: single small block scans the 196 partials (exclusive, in place)
__global__ __launch_bounds__(256) void scan2_kernel(int* __restrict__ partials)
{
    __shared__ int tmp[256];
    const int t = threadIdx.x;
    int v = (t < SCAN_NB) ? partials[t] : 0;
    tmp[t] = v;
    __syncthreads();
    for (int off = 1; off < 256; off <<= 1) {
        int u = (t >= off) ? tmp[t - off] : 0;
        __syncthreads();
        tmp[t] += u;
        __syncthreads();
    }
    if (t < SCAN_NB) partials[t] = tmp[t] - v;        // exclusive block offsets
}

// phase 3: add block offset, emit rowptr + cursor (+ static total)
__global__ __launch_bounds__(256) void scan3_kernel(const int* __restrict__ local,
                                                    const int* __restrict__ partials,
                                                    int* __restrict__ rowptr,
                                                    int* __restrict__ cursor)
{
    const int i = blockIdx.x * 256 + threadIdx.x;
    if (i < N_NODESC) {
        int r = local[i] + partials[blockIdx.x];
        rowptr[i] = r;
        cursor[i] = r;
    }
    if (i == 0) rowptr[N_NODESC] = N_EDGESC;          // total in-degree == edge count
}

__global__ void fill_kernel(const int* __restrict__ ei, int* __restrict__ cursor,
                            int* __restrict__ col) {
    int e = blockIdx.x * blockDim.x + threadIdx.x;
    if (e >= N_EDGESC) return;
    int d = ei[N_EDGESC + e];
    int pos = atomicAdd(&cursor[d], 1);
    col[pos] = ei[e];
}

// ---------- fused CSR-gather mean-agg + bias + Pr + BN partial sums ----------
// 8-way edge unroll: 8 independent bf16 row-loads in flight per wave per round.
// BN stats go to NREP replica slots to avoid same-address atomic serialization.
__global__ __launch_bounds__(128) void agg_combine_kernel(const int* __restrict__ rowptr,
                                                          const int* __restrict__ col,
                                                          const bf16_t* __restrict__ Plb,
                                                          const float* __restrict__ Pr,
                                                          const float* __restrict__ bias,
                                                          float* __restrict__ Hpre,
                                                          float* __restrict__ stats, int M)
{
    const int c = threadIdx.x;
    const float b = bias[c];
    float s = 0.f, s2 = 0.f;
    const int n0 = blockIdx.x * NB_AGG;
    for (int rr = 0; rr < NB_AGG; rr++) {
        int n = n0 + rr;
        if (n >= M) break;
        int lo = rowptr[n], hi = rowptr[n + 1];
        float a = 0.f;
        for (int e = lo; e < hi; e += 8) {
            int rem = hi - e;
            int idx[8];
#pragma unroll
            for (int j = 0; j < 8; j++) {
                int ee = e + j; if (ee > hi - 1) ee = hi - 1;
                idx[j] = col[ee];                       // 8 independent broadcast loads
            }
            float v[8];
#pragma unroll
            for (int j = 0; j < 8; j++)
                v[j] = (float)Plb[(size_t)idx[j] * HIDC + c];   // 8 loads in flight
#pragma unroll
            for (int j = 0; j < 8; j++)
                if (j < rem) a += v[j];                 // wave-uniform predicate
        }
        int d = hi - lo;
        float inv = 1.0f / (float)(d > 0 ? d : 1);
        float pre = fmaf(a, inv, b) + Pr[(size_t)n * HIDC + c];
        Hpre[(size_t)n * HIDC + c] = pre;
        s += pre; s2 += pre * pre;
    }
    const int rep = blockIdx.x & (NREP - 1);
    atomicAdd(&stats[rep * 256 + c], s);
    atomicAdd(&stats[rep * 256 + HIDC + c], s2);
}

// fold NREP replicas; stats -> per-channel scale/shift:  y = x*scale + shift
__global__ __launch_bounds__(128) void finalize_kernel(const float* __restrict__ stats,
                                                       const float* __restrict__ g,
                                                       const float* __restrict__ be,
                                                       float* __restrict__ sc, int M)
{
    int c = threadIdx.x;
    float sum = 0.f, sumsq = 0.f;
    for (int r = 0; r < NREP; r++) {
        sum   += stats[r * 256 + c];
        sumsq += stats[r * 256 + HIDC + c];
    }
    float invM = 1.0f / (float)M;
    float mean = sum * invM;
    float var  = sumsq * invM - mean * mean;
    float s = rsqrtf(var + BN_EPSC) * g[c];
    sc[c] = s;
    sc[HIDC + c] = be[c] - mean * s;
}

// pool with BN3 applied per element (transform precedes max; sign-safe)
__global__ __launch_bounds__(128) void pool_kernel(const float* __restrict__ Hpre,
                                                   const float* __restrict__ sc,
                                                   const int* __restrict__ batch,
                                                   float* __restrict__ pooled, int M)
{
    int gph = blockIdx.x;
    int c   = threadIdx.x;
    float s = sc[c], h = sc[HIDC + c];
    int lo = 0, hi = M;
    while (lo < hi) { int m = (lo + hi) >> 1; if (batch[m] < gph) lo = m + 1; else hi = m; }
    int lo2 = lo, hi2 = M;
    while (lo2 < hi2) { int m = (lo2 + hi2) >> 1; if (batch[m] < gph + 1) lo2 = m + 1; else hi2 = m; }
    float mx = -INFINITY;
    for (int rr = lo; rr < lo2; rr++)
        mx = fmaxf(mx, fmaf(Hpre[(size_t)rr * HIDC + c], s, h));
    pooled[gph * HIDC + c] = mx;
}

__global__ __launch_bounds__(128) void final_kernel(const float* __restrict__ pooled,
                                                    const float* __restrict__ W,
                                                    const float* __restrict__ bl,
                                                    float* __restrict__ out)
{
    __shared__ float sp[HIDC];
    int gph = blockIdx.x;
    int t   = threadIdx.x;
    sp[t] = pooled[gph * HIDC + t];
    __syncthreads();
    if (t < NCLSC) {
        float acc = bl[t];
        for (int c = 0; c < HIDC; c++) acc += sp[c] * W[t * HIDC + c];
        out[gph * NCLSC + t] = acc;
    }
}

extern "C" void kernel_launch(void* const* d_in, const int* in_sizes, int n_in,
                              void* d_out, int out_size, void* d_ws, size_t ws_size,
                              hipStream_t stream)
{
    const float* x     = (const float*)d_in[0];
    const int*   ei    = (const int*)d_in[1];
    const int*   batch = (const int*)d_in[2];
    const float* W1l = (const float*)d_in[3];
    const float* b1  = (const float*)d_in[4];
    const float* W1r = (const float*)d_in[5];
    const float* g1  = (const float*)d_in[6];
    const float* be1 = (const float*)d_in[7];
    const float* W2l = (const float*)d_in[8];
    const float* b2  = (const float*)d_in[9];
    const float* W2r = (const float*)d_in[10];
    const float* g2  = (const float*)d_in[11];
    const float* be2 = (const float*)d_in[12];
    const float* W3l = (const float*)d_in[13];
    const float* b3  = (const float*)d_in[14];
    const float* W3r = (const float*)d_in[15];
    const float* g3  = (const float*)d_in[16];
    const float* be3 = (const float*)d_in[17];
    const float* Wlin = (const float*)d_in[18];
    const float* blin = (const float*)d_in[19];

    const int M = N_NODESC;

    // workspace carve (all 16B-aligned: sizes are multiples of 16)
    char* w = (char*)d_ws;
    bf16_t* Plb  = (bf16_t*)w;  w += (size_t)M * HIDC * 2;   // 12.8 MB
    float* Pr    = (float*)w;   w += (size_t)M * HIDC * 4;   // 25.6 MB
    float* Hpre  = (float*)w;   w += (size_t)M * HIDC * 4;   // 25.6 MB
    int*   rowptr= (int*)w;     w += (size_t)(M + 16) * 4;
    int*   col   = (int*)w;     w += (size_t)N_EDGESC * 4;
    int*   cursor= (int*)w;     w += (size_t)M * 4;
    int*   degi  = (int*)w;     w += (size_t)M * 4;
    int*   slocal= (int*)w;     w += (size_t)M * 4;
    int*   spart = (int*)w;     w += 256 * 4;
    float* stats = (float*)w;   w += (size_t)NREP * 256 * 4; // 64 KB replicas
    float* sc    = (float*)w;   w += 256 * 4;
    float* pooled= (float*)w;   w += (size_t)N_GRAPHSC * HIDC * 4;

    const dim3 gemm_grid((M + 63) / 64, 2);
    const int agg_blocks = (M + NB_AGG - 1) / NB_AGG;
    const size_t stats_bytes = (size_t)NREP * 256 * 4;

    // ---- CSR build (per call: ws is re-poisoned) ----
    hipMemsetAsync(degi, 0, (size_t)M * 4, stream);
    degi_kernel<<<(N_EDGESC + 255) / 256, 256, 0, stream>>>(ei, degi);
    scan1_kernel<<<SCAN_NB, 256, 0, stream>>>(degi, slocal, spart);
    scan2_kernel<<<1, 256, 0, stream>>>(spart);
    scan3_kernel<<<SCAN_NB, 256, 0, stream>>>(slocal, spart, rowptr, cursor);
    fill_kernel<<<(N_EDGESC + 255) / 256, 256, 0, stream>>>(ei, cursor, col);

    // ---- layer 1 (K = 768, no BN on input) ----
    gemm_kernel<false><<<gemm_grid, 256, 0, stream>>>(x, W1l, W1r, nullptr, Plb, Pr, M, IN_DIMC);
    hipMemsetAsync(stats, 0, stats_bytes, stream);
    agg_combine_kernel<<<agg_blocks, 128, 0, stream>>>(rowptr, col, Plb, Pr, b1, Hpre, stats, M);
    finalize_kernel<<<1, 128, 0, stream>>>(stats, g1, be1, sc, M);

    // ---- layer 2 (K = 128, BN1+ReLU fused into A-staging) ----
    gemm_kernel<true><<<gemm_grid, 256, 0, stream>>>(Hpre, W2l, W2r, sc, Plb, Pr, M, HIDC);
    hipMemsetAsync(stats, 0, stats_bytes, stream);
    agg_combine_kernel<<<agg_blocks, 128, 0, stream>>>(rowptr, col, Plb, Pr, b2, Hpre, stats, M);
    finalize_kernel<<<1, 128, 0, stream>>>(stats, g2, be2, sc, M);

    // ---- layer 3 (K = 128, BN2+ReLU fused into A-staging) ----
    gemm_kernel<true><<<gemm_grid, 256, 0, stream>>>(Hpre, W3l, W3r, sc, Plb, Pr, M, HIDC);
    hipMemsetAsync(stats, 0, stats_bytes, stream);
    agg_combine_kernel<<<agg_blocks, 128, 0, stream>>>(rowptr, col, Plb, Pr, b3, Hpre, stats, M);
    finalize_kernel<<<1, 128, 0, stream>>>(stats, g3, be3, sc, M);

    // ---- pool (BN3 fused) + head ----
    pool_kernel<<<N_GRAPHSC, 128, 0, stream>>>(Hpre, sc, batch, pooled, M);
    final_kernel<<<N_GRAPHSC, 128, 0, stream>>>(pooled, Wlin, blin, (float*)d_out);
}

// Round 7
// 584.300 us; speedup vs baseline: 1.0205x; 1.0205x over previous
//
#include <hip/hip_runtime.h>

#define N_NODESC 50000
#define N_EDGESC 400000
#define N_GRAPHSC 128
#define IN_DIMC 768
#define HIDC 128
#define NCLSC 11
#define BN_EPSC 1e-5f
#define NB_AGG 8
#define NREP 64
#define SCAN_NB ((N_NODESC + 255) / 256)

typedef __bf16 bf16_t;
typedef __bf16 bf16x8 __attribute__((ext_vector_type(8)));
typedef float f32x4 __attribute__((ext_vector_type(4)));

typedef __attribute__((address_space(1))) void glb_void;
typedef __attribute__((address_space(3))) void lds_void;

__device__ __forceinline__ void cp16(const void* g, void* l) {
    // async global->LDS, 16B/lane; LDS dst = wave-uniform base + lane*16
    __builtin_amdgcn_global_load_lds((glb_void*)g, (lds_void*)l, 16, 0, 0);
}

__device__ __forceinline__ f32x4 mfma_16x16x32_bf16(bf16x8 a, bf16x8 b, f32x4 c) {
    return __builtin_amdgcn_mfma_f32_16x16x32_bf16(a, b, c, 0, 0, 0);
}

// [Cl|Cr] = BN?(A)[M,K] @ Wb^T, Wb [256,K] bf16 pre-converted.
// MODE 0: A fp32, no BN (layer 1).  MODE 1: A bf16, BN+ReLU applied post-LDS-read.
// Tile 128x128xBK32, blockIdx.y picks output half. Staging fully async
// (global_load_lds w=16), LDS XOR-swizzled so loader writes and b128 read
// phases are both bank-conflict-free. Outputs bf16.
template<int MODE>
__global__ __launch_bounds__(256) void gemm_kernel(const void* __restrict__ Av,
                                                   const bf16_t* __restrict__ Wb,
                                                   const float* __restrict__ sc,
                                                   bf16_t* __restrict__ Cl,
                                                   bf16_t* __restrict__ Cr,
                                                   int M, int K)
{
    constexpr int ABYTES = (MODE == 0) ? 128 * 32 * 4 : 128 * 32 * 2;
    constexpr int AISS   = (MODE == 0) ? 4 : 2;   // async issues per thread for A
    constexpr int AESZ   = (MODE == 0) ? 4 : 2;   // element size of A
    __shared__ __align__(16) unsigned char smem[ABYTES + 128 * 32 * 2];
    unsigned char* Asm = smem;
    unsigned char* Bsm = smem + ABYTES;

    const int t    = threadIdx.x;
    const int m0   = blockIdx.x * 128;
    const int half = blockIdx.y;
    const int wid  = t >> 6;
    const int lane = t & 63;
    const int wm   = (wid >> 1) * 64;
    const int wn   = (wid & 1) * 64;
    const int l16  = lane & 15;
    const int quad = lane >> 4;

    // ---- async-loader source pointers (swizzle folded into the GLOBAL side) ----
    const char* aSrc[AISS]; int aDst[AISS];
#pragma unroll
    for (int s = 0; s < AISS; s++) {
        int L = (s * 4 + wid) * 64 + lane;        // linear 16B-chunk slot
        int r, c;
        if (MODE == 0) { r = L >> 3; c = (L & 7) ^ (r & 7); }        // 8 chunks/row (f32)
        else           { r = L >> 2; c = (L & 3) ^ ((r >> 1) & 3); } // 4 chunks/row (bf16)
        int row = m0 + r; if (row > M - 1) row = M - 1;              // clamp, never stored
        aSrc[s] = (const char*)Av + ((size_t)row * K + (size_t)c * (16 / AESZ)) * AESZ;
        aDst[s] = (s * 4 + wid) * 1024;
    }
    const char* bSrc[2]; int bDst[2];
#pragma unroll
    for (int s = 0; s < 2; s++) {
        int L = (s * 4 + wid) * 64 + lane;
        int r = L >> 2;
        int c = (L & 3) ^ ((r >> 1) & 3);
        bSrc[s] = (const char*)(Wb + (size_t)(half * 128 + r) * K + c * 8);
        bDst[s] = (s * 4 + wid) * 1024;
    }

    // ---- fragment LDS byte offsets (loop-invariant, swizzled) ----
    int aOff[4][2], bOff[4];
#pragma unroll
    for (int i = 0; i < 4; i++) {
        int ra = wm + i * 16 + l16;
        if (MODE == 0) {
            aOff[i][0] = ra * 128 + (((2 * quad)     ^ (ra & 7)) * 16);
            aOff[i][1] = ra * 128 + (((2 * quad + 1) ^ (ra & 7)) * 16);
        } else {
            aOff[i][0] = ra * 64 + ((quad ^ ((ra >> 1) & 3)) * 16);
            aOff[i][1] = 0;
        }
        int rb = wn + i * 16 + l16;
        bOff[i] = rb * 64 + ((quad ^ ((rb >> 1) & 3)) * 16);
    }

    f32x4 acc[4][4] = {};

    for (int k0 = 0; k0 < K; k0 += 32) {
#pragma unroll
        for (int s = 0; s < AISS; s++)
            cp16(aSrc[s] + (size_t)k0 * AESZ, Asm + aDst[s]);
#pragma unroll
        for (int s = 0; s < 2; s++)
            cp16(bSrc[s] + (size_t)k0 * 2, Bsm + bDst[s]);
        __syncthreads();   // compiler emits vmcnt(0) drain before barrier

        bf16x8 af[4], bfr[4];
        if (MODE == 0) {
#pragma unroll
            for (int i = 0; i < 4; i++) {
                float4 u0 = *(const float4*)(Asm + aOff[i][0]);
                float4 u1 = *(const float4*)(Asm + aOff[i][1]);
                af[i][0] = (bf16_t)u0.x; af[i][1] = (bf16_t)u0.y;
                af[i][2] = (bf16_t)u0.z; af[i][3] = (bf16_t)u0.w;
                af[i][4] = (bf16_t)u1.x; af[i][5] = (bf16_t)u1.y;
                af[i][6] = (bf16_t)u1.z; af[i][7] = (bf16_t)u1.w;
            }
        } else {
            const int ch0 = k0 + quad * 8;
            float4 s0 = *(const float4*)&sc[ch0];
            float4 s1 = *(const float4*)&sc[ch0 + 4];
            float4 h0 = *(const float4*)&sc[HIDC + ch0];
            float4 h1 = *(const float4*)&sc[HIDC + ch0 + 4];
            float ss[8] = {s0.x, s0.y, s0.z, s0.w, s1.x, s1.y, s1.z, s1.w};
            float hh[8] = {h0.x, h0.y, h0.z, h0.w, h1.x, h1.y, h1.z, h1.w};
#pragma unroll
            for (int i = 0; i < 4; i++) {
                bf16x8 raw = *(const bf16x8*)(Asm + aOff[i][0]);
#pragma unroll
                for (int e = 0; e < 8; e++)
                    af[i][e] = (bf16_t)fmaxf(fmaf((float)raw[e], ss[e], hh[e]), 0.0f);
            }
        }
#pragma unroll
        for (int j = 0; j < 4; j++)
            bfr[j] = *(const bf16x8*)(Bsm + bOff[j]);
#pragma unroll
        for (int i = 0; i < 4; i++)
#pragma unroll
            for (int j = 0; j < 4; j++)
                acc[i][j] = mfma_16x16x32_bf16(af[i], bfr[j], acc[i][j]);
        __syncthreads();   // protect LDS before next iter's async writes
    }

    // C/D layout (m89-verified, empirically validated rounds 1-5)
    bf16_t* C = half ? Cr : Cl;
#pragma unroll
    for (int i = 0; i < 4; i++) {
        int rowb = m0 + wm + i * 16 + quad * 4;
#pragma unroll
        for (int j = 0; j < 4; j++) {
            int colh = wn + j * 16 + l16;
#pragma unroll
            for (int rr = 0; rr < 4; rr++) {
                int row = rowb + rr;
                if (row < M) C[(size_t)row * HIDC + colh] = (bf16_t)acc[i][j][rr];
            }
        }
    }
}

// weights [Wl;Wr] fp32 -> one [256,K] bf16 buffer
__global__ void wconv_kernel(const float* __restrict__ Wl, const float* __restrict__ Wr,
                             bf16_t* __restrict__ out, int KN)   // KN = 128*K
{
    int i = blockIdx.x * blockDim.x + threadIdx.x;
    if (i < KN)           out[i] = (bf16_t)Wl[i];
    else if (i < 2 * KN)  out[i] = (bf16_t)Wr[i - KN];
}

// ---------- CSR build ----------
__global__ void degi_kernel(const int* __restrict__ ei, int* __restrict__ degi) {
    int e = blockIdx.x * blockDim.x + threadIdx.x;
    if (e < N_EDGESC) atomicAdd(&degi[ei[N_EDGESC + e]], 1);
}

__global__ __launch_bounds__(256) void scan1_kernel(const int* __restrict__ degi,
                                                    int* __restrict__ local,
                                                    int* __restrict__ partials)
{
    __shared__ int tmp[256];
    const int t = threadIdx.x;
    const int i = blockIdx.x * 256 + t;
    int v = (i < N_NODESC) ? degi[i] : 0;
    tmp[t] = v;
    __syncthreads();
    for (int off = 1; off < 256; off <<= 1) {
        int u = (t >= off) ? tmp[t - off] : 0;
        __syncthreads();
        tmp[t] += u;
        __syncthreads();
    }
    if (i < N_NODESC) local[i] = tmp[t] - v;
    if (t == 255) partials[blockIdx.x] = tmp[255];
}

__global__ __launch_bounds__(256) void scan2_kernel(int* __restrict__ partials)
{
    __shared__ int tmp[256];
    const int t = threadIdx.x;
    int v = (t < SCAN_NB) ? partials[t] : 0;
    tmp[t] = v;
    __syncthreads();
    for (int off = 1; off < 256; off <<= 1) {
        int u = (t >= off) ? tmp[t - off] : 0;
        __syncthreads();
        tmp[t] += u;
        __syncthreads();
    }
    if (t < SCAN_NB) partials[t] = tmp[t] - v;
}

__global__ __launch_bounds__(256) void scan3_kernel(const int* __restrict__ local,
                                                    const int* __restrict__ partials,
                                                    int* __restrict__ rowptr,
                                                    int* __restrict__ cursor)
{
    const int i = blockIdx.x * 256 + threadIdx.x;
    if (i < N_NODESC) {
        int r = local[i] + partials[blockIdx.x];
        rowptr[i] = r;
        cursor[i] = r;
    }
    if (i == 0) rowptr[N_NODESC] = N_EDGESC;
}

__global__ void fill_kernel(const int* __restrict__ ei, int* __restrict__ cursor,
                            int* __restrict__ col) {
    int e = blockIdx.x * blockDim.x + threadIdx.x;
    if (e >= N_EDGESC) return;
    int d = ei[N_EDGESC + e];
    int pos = atomicAdd(&cursor[d], 1);
    col[pos] = ei[e];
}

// ---------- fused CSR-gather mean-agg + bias + Pr + BN partial sums ----------
__global__ __launch_bounds__(128) void agg_combine_kernel(const int* __restrict__ rowptr,
                                                          const int* __restrict__ col,
                                                          const bf16_t* __restrict__ Plb,
                                                          const bf16_t* __restrict__ Prb,
                                                          const float* __restrict__ bias,
                                                          bf16_t* __restrict__ Hb,
                                                          float* __restrict__ stats, int M)
{
    const int c = threadIdx.x;
    const float b = bias[c];
    float s = 0.f, s2 = 0.f;
    const int n0 = blockIdx.x * NB_AGG;
    for (int rr = 0; rr < NB_AGG; rr++) {
        int n = n0 + rr;
        if (n >= M) break;
        int lo = rowptr[n], hi = rowptr[n + 1];
        float a = 0.f;
        for (int e = lo; e < hi; e += 8) {
            int rem = hi - e;
            int idx[8];
#pragma unroll
            for (int j = 0; j < 8; j++) {
                int ee = e + j; if (ee > hi - 1) ee = hi - 1;
                idx[j] = col[ee];
            }
            float v[8];
#pragma unroll
            for (int j = 0; j < 8; j++)
                v[j] = (float)Plb[(size_t)idx[j] * HIDC + c];
#pragma unroll
            for (int j = 0; j < 8; j++)
                if (j < rem) a += v[j];
        }
        int d = hi - lo;
        float inv = 1.0f / (float)(d > 0 ? d : 1);
        float pre = fmaf(a, inv, b) + (float)Prb[(size_t)n * HIDC + c];
        Hb[(size_t)n * HIDC + c] = (bf16_t)pre;
        s += pre; s2 += pre * pre;
    }
    const int rep = blockIdx.x & (NREP - 1);
    atomicAdd(&stats[rep * 256 + c], s);
    atomicAdd(&stats[rep * 256 + HIDC + c], s2);
}

__global__ __launch_bounds__(128) void finalize_kernel(const float* __restrict__ stats,
                                                       const float* __restrict__ g,
                                                       const float* __restrict__ be,
                                                       float* __restrict__ sc, int M)
{
    int c = threadIdx.x;
    float sum = 0.f, sumsq = 0.f;
    for (int r = 0; r < NREP; r++) {
        sum   += stats[r * 256 + c];
        sumsq += stats[r * 256 + HIDC + c];
    }
    float invM = 1.0f / (float)M;
    float mean = sum * invM;
    float var  = sumsq * invM - mean * mean;
    float s = rsqrtf(var + BN_EPSC) * g[c];
    sc[c] = s;
    sc[HIDC + c] = be[c] - mean * s;
}

__global__ __launch_bounds__(128) void pool_kernel(const bf16_t* __restrict__ Hb,
                                                   const float* __restrict__ sc,
                                                   const int* __restrict__ batch,
                                                   float* __restrict__ pooled, int M)
{
    int gph = blockIdx.x;
    int c   = threadIdx.x;
    float s = sc[c], h = sc[HIDC + c];
    int lo = 0, hi = M;
    while (lo < hi) { int m = (lo + hi) >> 1; if (batch[m] < gph) lo = m + 1; else hi = m; }
    int lo2 = lo, hi2 = M;
    while (lo2 < hi2) { int m = (lo2 + hi2) >> 1; if (batch[m] < gph + 1) lo2 = m + 1; else hi2 = m; }
    float mx = -INFINITY;
    for (int rr = lo; rr < lo2; rr++)
        mx = fmaxf(mx, fmaf((float)Hb[(size_t)rr * HIDC + c], s, h));
    pooled[gph * HIDC + c] = mx;
}

__global__ __launch_bounds__(128) void final_kernel(const float* __restrict__ pooled,
                                                    const float* __restrict__ W,
                                                    const float* __restrict__ bl,
                                                    float* __restrict__ out)
{
    __shared__ float sp[HIDC];
    int gph = blockIdx.x;
    int t   = threadIdx.x;
    sp[t] = pooled[gph * HIDC + t];
    __syncthreads();
    if (t < NCLSC) {
        float acc = bl[t];
        for (int c = 0; c < HIDC; c++) acc += sp[c] * W[t * HIDC + c];
        out[gph * NCLSC + t] = acc;
    }
}

extern "C" void kernel_launch(void* const* d_in, const int* in_sizes, int n_in,
                              void* d_out, int out_size, void* d_ws, size_t ws_size,
                              hipStream_t stream)
{
    const float* x     = (const float*)d_in[0];
    const int*   ei    = (const int*)d_in[1];
    const int*   batch = (const int*)d_in[2];
    const float* W1l = (const float*)d_in[3];
    const float* b1  = (const float*)d_in[4];
    const float* W1r = (const float*)d_in[5];
    const float* g1  = (const float*)d_in[6];
    const float* be1 = (const float*)d_in[7];
    const float* W2l = (const float*)d_in[8];
    const float* b2  = (const float*)d_in[9];
    const float* W2r = (const float*)d_in[10];
    const float* g2  = (const float*)d_in[11];
    const float* be2 = (const float*)d_in[12];
    const float* W3l = (const float*)d_in[13];
    const float* b3  = (const float*)d_in[14];
    const float* W3r = (const float*)d_in[15];
    const float* g3  = (const float*)d_in[16];
    const float* be3 = (const float*)d_in[17];
    const float* Wlin = (const float*)d_in[18];
    const float* blin = (const float*)d_in[19];

    const int M = N_NODESC;

    // workspace carve (16B aligned)
    char* w = (char*)d_ws;
    bf16_t* Plb  = (bf16_t*)w;  w += (size_t)M * HIDC * 2;     // 12.8 MB
    bf16_t* Prb  = (bf16_t*)w;  w += (size_t)M * HIDC * 2;     // 12.8 MB
    bf16_t* Hb   = (bf16_t*)w;  w += (size_t)M * HIDC * 2;     // 12.8 MB
    bf16_t* Wb1  = (bf16_t*)w;  w += (size_t)256 * IN_DIMC * 2;
    bf16_t* Wb2  = (bf16_t*)w;  w += (size_t)256 * HIDC * 2;
    bf16_t* Wb3  = (bf16_t*)w;  w += (size_t)256 * HIDC * 2;
    int*   rowptr= (int*)w;     w += (size_t)(M + 16) * 4;
    int*   col   = (int*)w;     w += (size_t)N_EDGESC * 4;
    int*   cursor= (int*)w;     w += (size_t)M * 4;
    int*   degi  = (int*)w;     w += (size_t)M * 4;
    int*   slocal= (int*)w;     w += (size_t)M * 4;
    int*   spart = (int*)w;     w += 256 * 4;
    float* stats = (float*)w;   w += (size_t)NREP * 256 * 4;
    float* sc    = (float*)w;   w += 256 * 4;
    float* pooled= (float*)w;   w += (size_t)N_GRAPHSC * HIDC * 4;

    const dim3 gemm_grid((M + 127) / 128, 2);
    const int agg_blocks = (M + NB_AGG - 1) / NB_AGG;
    const size_t stats_bytes = (size_t)NREP * 256 * 4;

    // ---- weight pre-convert (independent of everything else) ----
    wconv_kernel<<<(2 * 128 * IN_DIMC + 255) / 256, 256, 0, stream>>>(W1l, W1r, Wb1, 128 * IN_DIMC);
    wconv_kernel<<<(2 * 128 * HIDC + 255) / 256, 256, 0, stream>>>(W2l, W2r, Wb2, 128 * HIDC);
    wconv_kernel<<<(2 * 128 * HIDC + 255) / 256, 256, 0, stream>>>(W3l, W3r, Wb3, 128 * HIDC);

    // ---- CSR build ----
    hipMemsetAsync(degi, 0, (size_t)M * 4, stream);
    degi_kernel<<<(N_EDGESC + 255) / 256, 256, 0, stream>>>(ei, degi);
    scan1_kernel<<<SCAN_NB, 256, 0, stream>>>(degi, slocal, spart);
    scan2_kernel<<<1, 256, 0, stream>>>(spart);
    scan3_kernel<<<SCAN_NB, 256, 0, stream>>>(slocal, spart, rowptr, cursor);
    fill_kernel<<<(N_EDGESC + 255) / 256, 256, 0, stream>>>(ei, cursor, col);

    // ---- layer 1 (K=768, A=x fp32, async f32 staging) ----
    gemm_kernel<0><<<gemm_grid, 256, 0, stream>>>(x, Wb1, nullptr, Plb, Prb, M, IN_DIMC);
    hipMemsetAsync(stats, 0, stats_bytes, stream);
    agg_combine_kernel<<<agg_blocks, 128, 0, stream>>>(rowptr, col, Plb, Prb, b1, Hb, stats, M);
    finalize_kernel<<<1, 128, 0, stream>>>(stats, g1, be1, sc, M);

    // ---- layer 2 (K=128, A=Hb bf16, BN1+ReLU applied post-LDS-read) ----
    gemm_kernel<1><<<gemm_grid, 256, 0, stream>>>(Hb, Wb2, sc, Plb, Prb, M, HIDC);
    hipMemsetAsync(stats, 0, stats_bytes, stream);
    agg_combine_kernel<<<agg_blocks, 128, 0, stream>>>(rowptr, col, Plb, Prb, b2, Hb, stats, M);
    finalize_kernel<<<1, 128, 0, stream>>>(stats, g2, be2, sc, M);

    // ---- layer 3 (K=128, BN2+ReLU fused) ----
    gemm_kernel<1><<<gemm_grid, 256, 0, stream>>>(Hb, Wb3, sc, Plb, Prb, M, HIDC);
    hipMemsetAsync(stats, 0, stats_bytes, stream);
    agg_combine_kernel<<<agg_blocks, 128, 0, stream>>>(rowptr, col, Plb, Prb, b3, Hb, stats, M);
    finalize_kernel<<<1, 128, 0, stream>>>(stats, g3, be3, sc, M);

    // ---- pool (BN3 fused) + head ----
    pool_kernel<<<N_GRAPHSC, 128, 0, stream>>>(Hb, sc, batch, pooled, M);
    final_kernel<<<N_GRAPHSC, 128, 0, stream>>>(pooled, Wlin, blin, (float*)d_out);
}